// Round 10
// baseline (210.605 us; speedup 1.0000x reference)
//
#include <hip/hip_runtime.h>

// LSTM RNN: B=2048, L=256 (257 scan steps), F=64, H=32, K=2.
// R11: R10 base (256 wgs x 8 batches, 4 waves, dup x2; 118us hot) + two
//  serial-chain cuts (wall = 257 x chain; only chain cuts matter):
//  (a) PARALLEL MFMA pair per gate: p=mfma(a0,Bf0,C0b) || r=mfma(a1,Bf1,zero);
//      y = fma(f, Dsel, p[e]+r[e]). Removes one dependent MFMA latency from
//      the chain (costs 8 off-chain VALU adds). Same for the logit pair.
//  (b) rr logit stash moved AFTER the barrier (was extending the rr wave's
//      pre-barrier lgkmcnt drain -> rotating straggler). Extra __syncthreads
//      before the epilogue covers the final stash's cross-wave visibility.
// Gate cols pre-scaled by -L2E (i,f,o) / -2*L2E (g); cs = -2*L2E*c.
// h exchange: 8x80-short double buffer (160B batch stride, 16B aligned).

typedef __attribute__((ext_vector_type(8))) short bf16x8;
typedef __attribute__((ext_vector_type(4))) float f32x4;

#define L2E 1.44269504088896340736f
#define LN2 0.69314718055994530942f

__device__ __forceinline__ short f2bf(float x) {
    unsigned u = __builtin_bit_cast(unsigned, x);
    unsigned r = (u + 0x7FFFu + ((u >> 16) & 1u)) >> 16;
    return (short)r;
}

__global__ __launch_bounds__(256) void lstm_kernel(
    const int* __restrict__ s, const float* __restrict__ g,
    const float* __restrict__ W_emb, const float* __restrict__ b_emb,
    const float* __restrict__ W_g1, const float* __restrict__ b_g1,
    const float* __restrict__ W_g2, const float* __restrict__ b_g2,
    const float* __restrict__ W_gh, const float* __restrict__ b_gh,
    const float* __restrict__ W_gc, const float* __restrict__ b_gc,
    const float* __restrict__ Wi, const float* __restrict__ Wh,
    const float* __restrict__ b_lstm, const float* __restrict__ W_amp,
    const float* __restrict__ b_amp, float* __restrict__ out)
{
    __shared__ float Bx[35 * 256];              // 0-31: W_g2@Wi; 32-33: W_emb@Wi; 34: const (pre-scaled)
    __shared__ unsigned char sp_l[260];         // packed tokens: bit b of sp_l[t] = s_pad[b][t], 8 batches
    __shared__ __align__(16) short Hb[2][640];  // h dbuf: [b(8) * 80 + f(64)] bf16
    __shared__ __align__(16) float dLb[256 * 8];// raw logit diffs (bias folded): [t(256)][b(8)]
    __shared__ float red2[8][32];               // epilogue partials

    const int tid = threadIdx.x;
    const int w   = tid >> 6;     // wave 0..3
    const int l   = tid & 63;     // lane
    const int n2  = l & 15;       // MFMA col
    const int q   = l >> 4;       // MFMA k-quad
    const int wgb = blockIdx.x * 8;

    // ---------- Setup: folded B rows into LDS, pre-scaled by activation constants ----------
    {
        const int n = tid;
        // cols [0,64)=i, [64,128)=f: -L2E; [128,192)=g: -2*L2E; [192,256)=o: -L2E
        const float sc = (n >= 128 && n < 192) ? (-2.0f * L2E) : (-L2E);
        float acc[35];
        #pragma unroll
        for (int i = 0; i < 35; ++i) acc[i] = 0.f;
        for (int f = 0; f < 64; ++f) {
            float wi = Wi[f * 256 + n] * sc;
            #pragma unroll
            for (int k = 0; k < 32; ++k) acc[k] += W_g2[k * 64 + f] * wi;  // uniform
            acc[32] += W_emb[f] * wi;
            acc[33] += W_emb[64 + f] * wi;
            acc[34] += (b_emb[f] + b_g2[f]) * wi;
        }
        acc[34] += b_lstm[n] * sc;
        #pragma unroll
        for (int i = 0; i < 35; ++i) Bx[i * 256 + n] = acc[i];
        // token staging: sp_l[t+1] bits = s[:, t] for 8 batch rows, sp_l[0] = 0
        unsigned v = 0;
        #pragma unroll
        for (int b = 0; b < 8; ++b)
            v |= (unsigned)(s[(wgb + b) * 256 + n] & 1) << b;
        sp_l[n + 1] = (unsigned char)v;
        if (n == 0) sp_l[0] = 0;
    }
    __syncthreads();

    // ---------- static fragments ----------
    bf16x8 Bf[4][2];          // Wh (K 0..63), pre-scaled
    float  Dsel[4];
    f32x4  C0b[4];            // STATIC C-init; elems {0,1}=batch 2q, {2,3}=batch 2q+1
    {
        bf16x8 B2f[4];
        float c0add[4];
        #pragma unroll
        for (int gi = 0; gi < 4; ++gi) {
            const int n = gi * 64 + w * 16 + n2;
            const float scg = (gi == 2) ? (-2.0f * L2E) : (-L2E);
            #pragma unroll
            for (int kf = 0; kf < 2; ++kf)
                #pragma unroll
                for (int j = 0; j < 8; ++j)
                    Bf[gi][kf][j] = f2bf(Wh[(kf * 32 + q * 8 + j) * 256 + n] * scg);
            #pragma unroll
            for (int j = 0; j < 8; ++j)
                B2f[gi][j] = f2bf(Bx[(q * 8 + j) * 256 + n]);
            c0add[gi] = Bx[32 * 256 + n] + Bx[34 * 256 + n];
            Dsel[gi]  = Bx[33 * 256 + n] - Bx[32 * 256 + n];
        }
        // Atv static A-frag; dup pattern: A row r -> batch r>>1
        const float g_a = g[wgb + ((l & 15) >> 1)];
        bf16x8 Atv;
        #pragma unroll
        for (int j = 0; j < 8; ++j) {
            int k = q * 8 + j;
            Atv[j] = f2bf(tanhf(g_a * W_g1[k] + b_g1[k]));
        }
        const f32x4 zero4 = {0.f, 0.f, 0.f, 0.f};
        #pragma unroll
        for (int gi = 0; gi < 4; ++gi) {
            f32x4 c = __builtin_amdgcn_mfma_f32_16x16x32_bf16(Atv, B2f[gi], zero4, 0, 0, 0);
            float cvA = c[0] + c0add[gi];   // rows q*4+{0,1} -> batch 2q
            float cvB = c[2] + c0add[gi];   // rows q*4+{2,3} -> batch 2q+1
            C0b[gi][0] = cvA; C0b[gi][1] = cvA; C0b[gi][2] = cvB; C0b[gi][3] = cvB;
        }
    }
    // logit DIFF column frags (col 0 = W_amp[:,1]-W_amp[:,0]; others 0) — NOT scaled
    bf16x8 BLd0, BLd1;
    f32x4 CL0;                 // static C-input, bias folded
    {
        #pragma unroll
        for (int j = 0; j < 8; ++j) {
            int k = q * 8 + j;
            BLd0[j] = (n2 == 0) ? f2bf(W_amp[k * 2 + 1] - W_amp[k * 2]) : (short)0;
            BLd1[j] = (n2 == 0) ? f2bf(W_amp[(k + 32) * 2 + 1] - W_amp[(k + 32) * 2]) : (short)0;
        }
        float bd = (n2 == 0) ? (b_amp[1] - b_amp[0]) : 0.f;
        CL0[0] = bd; CL0[1] = bd; CL0[2] = bd; CL0[3] = bd;
    }
    const f32x4 zn = {0.f, 0.f, 0.f, 0.f};   // static zero C for the parallel halves

    // ---------- state init (cs = -2*L2E*c, pre-scaled) ----------
    const int fcol   = w * 16 + n2;      // gate-phase f ownership
    const int bA     = q * 2;            // gate-phase batches (MFMA rows q*4+{0,1} / {2,3})
    const int bB     = bA + 1;
    const int haddrA = bA * 80 + fcol;
    const int haddrB = haddrA + 80;
    float csA, csB;
    {
        float gA = g[wgb + bA], gB = g[wgb + bB];
        csA = (-2.0f * L2E) * (gA * W_gc[fcol] + b_gc[fcol]);
        csB = (-2.0f * L2E) * (gB * W_gc[fcol] + b_gc[fcol]);
        Hb[0][haddrA] = f2bf(gA * W_gh[fcol] + b_gh[fcol]);
        Hb[0][haddrB] = f2bf(gB * W_gh[fcol] + b_gh[fcol]);
    }
    __syncthreads();

    // ---------- main recurrence ----------
    const int ra = ((l & 15) >> 1) * 80 + q * 8;   // A-frag: batch (l&15)>>1, feats q*8..+8
    unsigned spt = 0;                              // sp_l[0]

    auto step = [&](int t, int rb, int slot, bool doGate) {
        bf16x8 a0 = *(const bf16x8*)&Hb[rb][ra];
        bf16x8 a1 = *(const bf16x8*)&Hb[rb][ra + 32];
        unsigned spt_n = sp_l[t + 1];             // prefetch next token byte
        const float fA = (float)((spt >> bA) & 1u);   // tokens s_pad[t]
        const float fB = (float)((spt >> bB) & 1u);

        // parallel (independent) MFMA halves: one MFMA latency on the chain
        f32x4 p[4], r[4];
        #pragma unroll
        for (int gi = 0; gi < 4; ++gi) {
            p[gi] = __builtin_amdgcn_mfma_f32_16x16x32_bf16(a0, Bf[gi][0], C0b[gi], 0, 0, 0);
            r[gi] = __builtin_amdgcn_mfma_f32_16x16x32_bf16(a1, Bf[gi][1], zn, 0, 0, 0);
        }

        const bool rr = (w == slot) && (t >= 1);  // slot-static round-robin logit wave
        float dA = 0.f, dB = 0.f;
        if (rr) {
            f32x4 pL = __builtin_amdgcn_mfma_f32_16x16x32_bf16(a0, BLd0, CL0, 0, 0, 0);
            f32x4 rL = __builtin_amdgcn_mfma_f32_16x16x32_bf16(a1, BLd1, zn, 0, 0, 0);
            dA = pL[0] + rL[0];
            dB = pL[2] + rL[2];
        }

        if (doGate) {
            // merge halves + token fold (elements 0,2 only)
            float yiA = __builtin_fmaf(fA, Dsel[0], p[0][0] + r[0][0]);
            float yiB = __builtin_fmaf(fB, Dsel[0], p[0][2] + r[0][2]);
            float yfA = __builtin_fmaf(fA, Dsel[1], p[1][0] + r[1][0]);
            float yfB = __builtin_fmaf(fB, Dsel[1], p[1][2] + r[1][2]);
            float ygA = __builtin_fmaf(fA, Dsel[2], p[2][0] + r[2][0]);
            float ygB = __builtin_fmaf(fB, Dsel[2], p[2][2] + r[2][2]);
            float yoA = __builtin_fmaf(fA, Dsel[3], p[3][0] + r[3][0]);
            float yoB = __builtin_fmaf(fB, Dsel[3], p[3][2] + r[3][2]);
            // y's are -L2E*z (i,f,o) and -2*L2E*z (g)
            float siA = __builtin_amdgcn_rcpf(1.0f + __builtin_amdgcn_exp2f(yiA));
            float siB = __builtin_amdgcn_rcpf(1.0f + __builtin_amdgcn_exp2f(yiB));
            float sfA = __builtin_amdgcn_rcpf(1.0f + __builtin_amdgcn_exp2f(yfA));
            float sfB = __builtin_amdgcn_rcpf(1.0f + __builtin_amdgcn_exp2f(yfB));
            float rgA = __builtin_amdgcn_rcpf(1.0f + __builtin_amdgcn_exp2f(ygA));
            float rgB = __builtin_amdgcn_rcpf(1.0f + __builtin_amdgcn_exp2f(ygB));
            float soA = __builtin_amdgcn_rcpf(1.0f + __builtin_amdgcn_exp2f(yoA));
            float soB = __builtin_amdgcn_rcpf(1.0f + __builtin_amdgcn_exp2f(yoB));
            float tgsA = __builtin_fmaf(-4.0f * L2E, rgA, 2.0f * L2E);   // -2*L2E*tanh(zg)
            float tgsB = __builtin_fmaf(-4.0f * L2E, rgB, 2.0f * L2E);
            csA = __builtin_fmaf(sfA, csA, siA * tgsA);
            csB = __builtin_fmaf(sfB, csB, siB * tgsB);
            float so2A = soA + soA;               // off-chain (ready before r5)
            float so2B = soB + soB;
            float r5A = __builtin_amdgcn_rcpf(1.0f + __builtin_amdgcn_exp2f(csA));
            float r5B = __builtin_amdgcn_rcpf(1.0f + __builtin_amdgcn_exp2f(csB));
            float hA  = __builtin_fmaf(so2A, r5A, -soA);   // so*(2*r5-1)
            float hB  = __builtin_fmaf(so2B, r5B, -soB);
            unsigned hv;
            asm("v_cvt_pk_bf16_f32 %0, %1, %2" : "=v"(hv) : "v"(hA), "v"(hB));
            Hb[1 - rb][haddrA] = (short)hv;
            Hb[1 - rb][haddrB] = (short)(hv >> 16);
        }
        spt = spt_n;
        __syncthreads();

        if (rr && n2 == 0) {   // stash AFTER barrier: off the pre-barrier drain,
            float2 d2;         // overlaps next step's ds_read latency window
            d2.x = dA; d2.y = dB;
            *(float2*)&dLb[(t - 1) * 8 + 2 * q] = d2;
        }
    };

    for (int t0 = 0; t0 < 256; t0 += 4) {
        step(t0 + 0, 0, 0, true);
        step(t0 + 1, 1, 1, true);
        step(t0 + 2, 0, 2, true);
        step(t0 + 3, 1, 3, true);
    }
    step(256, 0, 0, false);   // final logit step, no gate phase

    __syncthreads();          // cover the post-barrier t=256 stash (cross-wave)

    // ---------- epilogue: deferred softplus (3 stages) ----------
    {
        // stage 1: thread tid handles stash row t=tid (8 batches); bias already folded
        unsigned bits = (unsigned)sp_l[tid + 1];
        f32x4 v0 = *(const f32x4*)&dLb[tid * 8];
        f32x4 v1 = *(const f32x4*)&dLb[tid * 8 + 4];
        f32x4 s0, s1;
        #pragma unroll
        for (int r = 0; r < 4; ++r) {
            float x0 = ((bits >> r) & 1u) ? -v0[r] : v0[r];    // l_other - l_token
            s0[r] = __builtin_amdgcn_logf(1.0f + __builtin_amdgcn_exp2f(L2E * x0));
            float x1 = ((bits >> (r + 4)) & 1u) ? -v1[r] : v1[r];
            s1[r] = __builtin_amdgcn_logf(1.0f + __builtin_amdgcn_exp2f(L2E * x1));
        }
        *(f32x4*)&dLb[tid * 8]     = s0;
        *(f32x4*)&dLb[tid * 8 + 4] = s1;
        __syncthreads();
        // stage 2: thread (b = tid>>5, j = tid&31) sums 8 rows
        {
            int b = tid >> 5, j = tid & 31;
            float sum = 0.f;
            #pragma unroll
            for (int k = 0; k < 8; ++k)
                sum += dLb[(j * 8 + k) * 8 + b];
            red2[b][j] = sum;
        }
        __syncthreads();
        // stage 3
        if (tid < 8) {
            float sum = 0.f;
            #pragma unroll
            for (int j2 = 0; j2 < 32; ++j2) sum += red2[tid][j2];
            out[wgb + tid] = -LN2 * sum;
        }
    }
}

extern "C" void kernel_launch(void* const* d_in, const int* in_sizes, int n_in,
                              void* d_out, int out_size, void* d_ws, size_t ws_size,
                              hipStream_t stream) {
    (void)in_sizes; (void)n_in; (void)out_size; (void)d_ws; (void)ws_size;
    const int*   s      = (const int*)d_in[0];
    const float* g      = (const float*)d_in[1];
    const float* W_emb  = (const float*)d_in[2];
    const float* b_emb  = (const float*)d_in[3];
    const float* W_g1   = (const float*)d_in[4];
    const float* b_g1   = (const float*)d_in[5];
    const float* W_g2   = (const float*)d_in[6];
    const float* b_g2   = (const float*)d_in[7];
    const float* W_gh   = (const float*)d_in[8];
    const float* b_gh   = (const float*)d_in[9];
    const float* W_gc   = (const float*)d_in[10];
    const float* b_gc   = (const float*)d_in[11];
    const float* Wi     = (const float*)d_in[12];
    const float* Wh     = (const float*)d_in[13];
    const float* b_lstm = (const float*)d_in[14];
    const float* W_amp  = (const float*)d_in[15];
    const float* b_amp  = (const float*)d_in[16];
    float* out = (float*)d_out;

    lstm_kernel<<<256, 256, 0, stream>>>(s, g, W_emb, b_emb, W_g1, b_g1, W_g2, b_g2,
                                         W_gh, b_gh, W_gc, b_gc, Wi, Wh, b_lstm,
                                         W_amp, b_amp, out);
}

// Round 11
// 192.558 us; speedup vs baseline: 1.0937x; 1.0937x over previous
//
#include <hip/hip_runtime.h>

// LSTM RNN: B=2048, L=256 (257 scan steps), F=64, H=32, K=2.
// R12: R10 base restored exactly (256 wgs x 8 batches, 4 waves, dup x2,
//  chained MFMA C-forwarding — R9/R11 both proved the C-chain must not be
//  touched), with ONE isolated change: the rr wave's logit block (2 MFMA +
//  masked stash) moves AFTER the barrier. Pre-barrier, the rr wave was a
//  rotating straggler (+2 MFMA + ds_write) stretching every rendezvous;
//  post-barrier it overlaps the next step's ds_read stall window (a0/a1
//  stay live in regs; dLb is only read in the epilogue; extra __syncthreads
//  before the epilogue covers the final stash).
// Gate cols pre-scaled by -L2E (i,f,o) / -2*L2E (g); cs = -2*L2E*c.
// h exchange: 8x80-short double buffer (160B batch stride, 16B aligned).

typedef __attribute__((ext_vector_type(8))) short bf16x8;
typedef __attribute__((ext_vector_type(4))) float f32x4;

#define L2E 1.44269504088896340736f
#define LN2 0.69314718055994530942f

__device__ __forceinline__ short f2bf(float x) {
    unsigned u = __builtin_bit_cast(unsigned, x);
    unsigned r = (u + 0x7FFFu + ((u >> 16) & 1u)) >> 16;
    return (short)r;
}

__global__ __launch_bounds__(256) void lstm_kernel(
    const int* __restrict__ s, const float* __restrict__ g,
    const float* __restrict__ W_emb, const float* __restrict__ b_emb,
    const float* __restrict__ W_g1, const float* __restrict__ b_g1,
    const float* __restrict__ W_g2, const float* __restrict__ b_g2,
    const float* __restrict__ W_gh, const float* __restrict__ b_gh,
    const float* __restrict__ W_gc, const float* __restrict__ b_gc,
    const float* __restrict__ Wi, const float* __restrict__ Wh,
    const float* __restrict__ b_lstm, const float* __restrict__ W_amp,
    const float* __restrict__ b_amp, float* __restrict__ out)
{
    __shared__ float Bx[35 * 256];              // 0-31: W_g2@Wi; 32-33: W_emb@Wi; 34: const (pre-scaled)
    __shared__ unsigned char sp_l[260];         // packed tokens: bit b of sp_l[t] = s_pad[b][t], 8 batches
    __shared__ __align__(16) short Hb[2][640];  // h dbuf: [b(8) * 80 + f(64)] bf16
    __shared__ __align__(16) float dLb[256 * 8];// raw logit diffs (bias folded): [t(256)][b(8)]
    __shared__ float red2[8][32];               // epilogue partials

    const int tid = threadIdx.x;
    const int w   = tid >> 6;     // wave 0..3
    const int l   = tid & 63;     // lane
    const int n2  = l & 15;       // MFMA col
    const int q   = l >> 4;       // MFMA k-quad
    const int wgb = blockIdx.x * 8;

    // ---------- Setup: folded B rows into LDS, pre-scaled by activation constants ----------
    {
        const int n = tid;
        // cols [0,64)=i, [64,128)=f: -L2E; [128,192)=g: -2*L2E; [192,256)=o: -L2E
        const float sc = (n >= 128 && n < 192) ? (-2.0f * L2E) : (-L2E);
        float acc[35];
        #pragma unroll
        for (int i = 0; i < 35; ++i) acc[i] = 0.f;
        for (int f = 0; f < 64; ++f) {
            float wi = Wi[f * 256 + n] * sc;
            #pragma unroll
            for (int k = 0; k < 32; ++k) acc[k] += W_g2[k * 64 + f] * wi;  // uniform
            acc[32] += W_emb[f] * wi;
            acc[33] += W_emb[64 + f] * wi;
            acc[34] += (b_emb[f] + b_g2[f]) * wi;
        }
        acc[34] += b_lstm[n] * sc;
        #pragma unroll
        for (int i = 0; i < 35; ++i) Bx[i * 256 + n] = acc[i];
        // token staging: sp_l[t+1] bits = s[:, t] for 8 batch rows, sp_l[0] = 0
        unsigned v = 0;
        #pragma unroll
        for (int b = 0; b < 8; ++b)
            v |= (unsigned)(s[(wgb + b) * 256 + n] & 1) << b;
        sp_l[n + 1] = (unsigned char)v;
        if (n == 0) sp_l[0] = 0;
    }
    __syncthreads();

    // ---------- static fragments ----------
    bf16x8 Bf[4][2];          // Wh (K 0..63), pre-scaled
    float  Dsel[4];
    f32x4  C0b[4];            // STATIC C-init; elems {0,1}=batch 2q, {2,3}=batch 2q+1
    {
        bf16x8 B2f[4];
        float c0add[4];
        #pragma unroll
        for (int gi = 0; gi < 4; ++gi) {
            const int n = gi * 64 + w * 16 + n2;
            const float scg = (gi == 2) ? (-2.0f * L2E) : (-L2E);
            #pragma unroll
            for (int kf = 0; kf < 2; ++kf)
                #pragma unroll
                for (int j = 0; j < 8; ++j)
                    Bf[gi][kf][j] = f2bf(Wh[(kf * 32 + q * 8 + j) * 256 + n] * scg);
            #pragma unroll
            for (int j = 0; j < 8; ++j)
                B2f[gi][j] = f2bf(Bx[(q * 8 + j) * 256 + n]);
            c0add[gi] = Bx[32 * 256 + n] + Bx[34 * 256 + n];
            Dsel[gi]  = Bx[33 * 256 + n] - Bx[32 * 256 + n];
        }
        // Atv static A-frag; dup pattern: A row r -> batch r>>1
        const float g_a = g[wgb + ((l & 15) >> 1)];
        bf16x8 Atv;
        #pragma unroll
        for (int j = 0; j < 8; ++j) {
            int k = q * 8 + j;
            Atv[j] = f2bf(tanhf(g_a * W_g1[k] + b_g1[k]));
        }
        const f32x4 zero4 = {0.f, 0.f, 0.f, 0.f};
        #pragma unroll
        for (int gi = 0; gi < 4; ++gi) {
            f32x4 c = __builtin_amdgcn_mfma_f32_16x16x32_bf16(Atv, B2f[gi], zero4, 0, 0, 0);
            float cvA = c[0] + c0add[gi];   // rows q*4+{0,1} -> batch 2q
            float cvB = c[2] + c0add[gi];   // rows q*4+{2,3} -> batch 2q+1
            C0b[gi][0] = cvA; C0b[gi][1] = cvA; C0b[gi][2] = cvB; C0b[gi][3] = cvB;
        }
    }
    // logit DIFF column frags (col 0 = W_amp[:,1]-W_amp[:,0]; others 0) — NOT scaled
    bf16x8 BLd0, BLd1;
    f32x4 CL0;                 // static C-input, bias folded
    {
        #pragma unroll
        for (int j = 0; j < 8; ++j) {
            int k = q * 8 + j;
            BLd0[j] = (n2 == 0) ? f2bf(W_amp[k * 2 + 1] - W_amp[k * 2]) : (short)0;
            BLd1[j] = (n2 == 0) ? f2bf(W_amp[(k + 32) * 2 + 1] - W_amp[(k + 32) * 2]) : (short)0;
        }
        float bd = (n2 == 0) ? (b_amp[1] - b_amp[0]) : 0.f;
        CL0[0] = bd; CL0[1] = bd; CL0[2] = bd; CL0[3] = bd;
    }

    // ---------- state init (cs = -2*L2E*c, pre-scaled) ----------
    const int fcol   = w * 16 + n2;      // gate-phase f ownership
    const int bA     = q * 2;            // gate-phase batches (MFMA rows q*4+{0,1} / {2,3})
    const int bB     = bA + 1;
    const int haddrA = bA * 80 + fcol;
    const int haddrB = haddrA + 80;
    float csA, csB;
    {
        float gA = g[wgb + bA], gB = g[wgb + bB];
        csA = (-2.0f * L2E) * (gA * W_gc[fcol] + b_gc[fcol]);
        csB = (-2.0f * L2E) * (gB * W_gc[fcol] + b_gc[fcol]);
        Hb[0][haddrA] = f2bf(gA * W_gh[fcol] + b_gh[fcol]);
        Hb[0][haddrB] = f2bf(gB * W_gh[fcol] + b_gh[fcol]);
    }
    __syncthreads();

    // ---------- main recurrence ----------
    const int ra = ((l & 15) >> 1) * 80 + q * 8;   // A-frag: batch (l&15)>>1, feats q*8..+8
    unsigned spt = 0;                              // sp_l[0]

    auto step = [&](int t, int rb, int slot, bool doGate) {
        bf16x8 a0 = *(const bf16x8*)&Hb[rb][ra];
        bf16x8 a1 = *(const bf16x8*)&Hb[rb][ra + 32];
        unsigned spt_n = sp_l[t + 1];             // prefetch next token byte
        const float fA = (float)((spt >> bA) & 1u);   // tokens s_pad[t]
        const float fB = (float)((spt >> bB) & 1u);

        f32x4 acc[4];
        #pragma unroll
        for (int gi = 0; gi < 4; ++gi) {
            f32x4 a = __builtin_amdgcn_mfma_f32_16x16x32_bf16(a1, Bf[gi][1], C0b[gi], 0, 0, 0);
            acc[gi] = __builtin_amdgcn_mfma_f32_16x16x32_bf16(a0, Bf[gi][0], a, 0, 0, 0);
        }

        const bool rr = (w == slot) && (t >= 1);  // slot-static round-robin logit wave

        if (doGate) {
            // token fold post-MFMA (elements 0,2 only) — R5 form
            float yiA = __builtin_fmaf(fA, Dsel[0], acc[0][0]);
            float yiB = __builtin_fmaf(fB, Dsel[0], acc[0][2]);
            float yfA = __builtin_fmaf(fA, Dsel[1], acc[1][0]);
            float yfB = __builtin_fmaf(fB, Dsel[1], acc[1][2]);
            float ygA = __builtin_fmaf(fA, Dsel[2], acc[2][0]);
            float ygB = __builtin_fmaf(fB, Dsel[2], acc[2][2]);
            float yoA = __builtin_fmaf(fA, Dsel[3], acc[3][0]);
            float yoB = __builtin_fmaf(fB, Dsel[3], acc[3][2]);
            // y's are -L2E*z (i,f,o) and -2*L2E*z (g)
            float siA = __builtin_amdgcn_rcpf(1.0f + __builtin_amdgcn_exp2f(yiA));
            float siB = __builtin_amdgcn_rcpf(1.0f + __builtin_amdgcn_exp2f(yiB));
            float sfA = __builtin_amdgcn_rcpf(1.0f + __builtin_amdgcn_exp2f(yfA));
            float sfB = __builtin_amdgcn_rcpf(1.0f + __builtin_amdgcn_exp2f(yfB));
            float rgA = __builtin_amdgcn_rcpf(1.0f + __builtin_amdgcn_exp2f(ygA));
            float rgB = __builtin_amdgcn_rcpf(1.0f + __builtin_amdgcn_exp2f(ygB));
            float soA = __builtin_amdgcn_rcpf(1.0f + __builtin_amdgcn_exp2f(yoA));
            float soB = __builtin_amdgcn_rcpf(1.0f + __builtin_amdgcn_exp2f(yoB));
            float tgsA = __builtin_fmaf(-4.0f * L2E, rgA, 2.0f * L2E);   // -2*L2E*tanh(zg)
            float tgsB = __builtin_fmaf(-4.0f * L2E, rgB, 2.0f * L2E);
            csA = __builtin_fmaf(sfA, csA, siA * tgsA);
            csB = __builtin_fmaf(sfB, csB, siB * tgsB);
            float so2A = soA + soA;               // off-chain (ready before r5)
            float so2B = soB + soB;
            float r5A = __builtin_amdgcn_rcpf(1.0f + __builtin_amdgcn_exp2f(csA));
            float r5B = __builtin_amdgcn_rcpf(1.0f + __builtin_amdgcn_exp2f(csB));
            float hA  = __builtin_fmaf(so2A, r5A, -soA);   // so*(2*r5-1)
            float hB  = __builtin_fmaf(so2B, r5B, -soB);
            unsigned hv;
            asm("v_cvt_pk_bf16_f32 %0, %1, %2" : "=v"(hv) : "v"(hA), "v"(hB));
            Hb[1 - rb][haddrA] = (short)hv;
            Hb[1 - rb][haddrB] = (short)(hv >> 16);
        }
        spt = spt_n;
        __syncthreads();

        if (rr) {   // POST-barrier: overlaps the next step's ds_read stall window.
            f32x4 aL = __builtin_amdgcn_mfma_f32_16x16x32_bf16(a1, BLd1, CL0, 0, 0, 0);
            aL = __builtin_amdgcn_mfma_f32_16x16x32_bf16(a0, BLd0, aL, 0, 0, 0);
            if (n2 == 0) {                        // stash RAW diffs; sign+softplus in epilogue
                float2 d2; d2.x = aL[0]; d2.y = aL[2];
                *(float2*)&dLb[(t - 1) * 8 + 2 * q] = d2;
            }
        }
    };

    for (int t0 = 0; t0 < 256; t0 += 4) {
        step(t0 + 0, 0, 0, true);
        step(t0 + 1, 1, 1, true);
        step(t0 + 2, 0, 2, true);
        step(t0 + 3, 1, 3, true);
    }
    step(256, 0, 0, false);   // final logit step, no gate phase

    __syncthreads();          // cover the post-barrier stashes (cross-wave) before epilogue

    // ---------- epilogue: deferred softplus (3 stages) ----------
    {
        // stage 1: thread tid handles stash row t=tid (8 batches); bias already folded
        unsigned bits = (unsigned)sp_l[tid + 1];
        f32x4 v0 = *(const f32x4*)&dLb[tid * 8];
        f32x4 v1 = *(const f32x4*)&dLb[tid * 8 + 4];
        f32x4 s0, s1;
        #pragma unroll
        for (int r = 0; r < 4; ++r) {
            float x0 = ((bits >> r) & 1u) ? -v0[r] : v0[r];    // l_other - l_token
            s0[r] = __builtin_amdgcn_logf(1.0f + __builtin_amdgcn_exp2f(L2E * x0));
            float x1 = ((bits >> (r + 4)) & 1u) ? -v1[r] : v1[r];
            s1[r] = __builtin_amdgcn_logf(1.0f + __builtin_amdgcn_exp2f(L2E * x1));
        }
        *(f32x4*)&dLb[tid * 8]     = s0;
        *(f32x4*)&dLb[tid * 8 + 4] = s1;
        __syncthreads();
        // stage 2: thread (b = tid>>5, j = tid&31) sums 8 rows
        {
            int b = tid >> 5, j = tid & 31;
            float sum = 0.f;
            #pragma unroll
            for (int k = 0; k < 8; ++k)
                sum += dLb[(j * 8 + k) * 8 + b];
            red2[b][j] = sum;
        }
        __syncthreads();
        // stage 3
        if (tid < 8) {
            float sum = 0.f;
            #pragma unroll
            for (int j2 = 0; j2 < 32; ++j2) sum += red2[tid][j2];
            out[wgb + tid] = -LN2 * sum;
        }
    }
}

extern "C" void kernel_launch(void* const* d_in, const int* in_sizes, int n_in,
                              void* d_out, int out_size, void* d_ws, size_t ws_size,
                              hipStream_t stream) {
    (void)in_sizes; (void)n_in; (void)out_size; (void)d_ws; (void)ws_size;
    const int*   s      = (const int*)d_in[0];
    const float* g      = (const float*)d_in[1];
    const float* W_emb  = (const float*)d_in[2];
    const float* b_emb  = (const float*)d_in[3];
    const float* W_g1   = (const float*)d_in[4];
    const float* b_g1   = (const float*)d_in[5];
    const float* W_g2   = (const float*)d_in[6];
    const float* b_g2   = (const float*)d_in[7];
    const float* W_gh   = (const float*)d_in[8];
    const float* b_gh   = (const float*)d_in[9];
    const float* W_gc   = (const float*)d_in[10];
    const float* b_gc   = (const float*)d_in[11];
    const float* Wi     = (const float*)d_in[12];
    const float* Wh     = (const float*)d_in[13];
    const float* b_lstm = (const float*)d_in[14];
    const float* W_amp  = (const float*)d_in[15];
    const float* b_amp  = (const float*)d_in[16];
    float* out = (float*)d_out;

    lstm_kernel<<<256, 256, 0, stream>>>(s, g, W_emb, b_emb, W_g1, b_g1, W_g2, b_g2,
                                         W_gh, b_gh, W_gc, b_gc, Wi, Wh, b_lstm,
                                         W_amp, b_amp, out);
}